// Round 1
// baseline (56439.697 us; speedup 1.0000x reference)
//
#include <hip/hip_runtime.h>
#include <hip/hip_bf16.h>
#include <math.h>
#include <utility>

#define BATCH 8
#define T_STEPS 20
#define VOCAB 22
#define EDIM 64
#define HDIM 512
#define START_TOK 20

// ---------------- conv 3x3 SAME + relu (direct) ----------------
__global__ __launch_bounds__(256) void conv3x3_relu_kernel(
    const float* __restrict__ x, const float* __restrict__ w,
    const float* __restrict__ bias, float* __restrict__ y,
    int Cin, int Cout, int Hs, int Ws)
{
    int HW = Hs * Ws;
    int sp = blockIdx.x * 256 + threadIdx.x;
    if (sp >= HW) return;
    int h = sp / Ws;
    int col = sp - h * Ws;
    int o = blockIdx.y;
    int n = blockIdx.z;
    const float* xn = x + (size_t)n * Cin * HW;
    const float* wo = w + (size_t)o * Cin * 9;
    float acc = bias[o];
    if (h >= 1 && h < Hs - 1 && col >= 1 && col < Ws - 1) {
        const float* xr = xn + (size_t)(h - 1) * Ws + (col - 1);
        for (int i = 0; i < Cin; ++i) {
            const float* xc = xr + (size_t)i * HW;
            const float* wc = wo + i * 9;
            acc += xc[0] * wc[0] + xc[1] * wc[1] + xc[2] * wc[2];
            acc += xc[Ws] * wc[3] + xc[Ws + 1] * wc[4] + xc[Ws + 2] * wc[5];
            acc += xc[2 * Ws] * wc[6] + xc[2 * Ws + 1] * wc[7] + xc[2 * Ws + 2] * wc[8];
        }
    } else {
        for (int i = 0; i < Cin; ++i) {
            const float* xc = xn + (size_t)i * HW;
            const float* wc = wo + i * 9;
            #pragma unroll
            for (int kh = 0; kh < 3; ++kh) {
                int hh = h + kh - 1;
                if (hh < 0 || hh >= Hs) continue;
                #pragma unroll
                for (int kw = 0; kw < 3; ++kw) {
                    int cc = col + kw - 1;
                    if (cc < 0 || cc >= Ws) continue;
                    acc += xc[hh * Ws + cc] * wc[kh * 3 + kw];
                }
            }
        }
    }
    y[((size_t)n * Cout + o) * HW + sp] = fmaxf(acc, 0.f);
}

// ---------------- 2x2 maxpool stride 2 ----------------
__global__ __launch_bounds__(256) void maxpool2_kernel(
    const float* __restrict__ x, float* __restrict__ y, int C, int Hin, int Win)
{
    int Ho = Hin >> 1, Wo = Win >> 1;
    size_t total = (size_t)BATCH * C * Ho * Wo;
    size_t i = (size_t)blockIdx.x * 256 + threadIdx.x;
    if (i >= total) return;
    int wo = (int)(i % Wo);
    size_t r = i / Wo;
    int ho = (int)(r % Ho);
    r /= Ho;  // r = n*C + c
    const float* xp = x + (r * Hin + 2 * (size_t)ho) * Win + 2 * wo;
    float m = fmaxf(fmaxf(xp[0], xp[1]), fmaxf(xp[Win], xp[Win + 1]));
    y[i] = m;
}

// ---------------- linear: Y[b][o] = act(sum_k X[b][k]*W[o][k] + bias[o]) ----
// one block per output column o, 8 batch rows per block
__global__ __launch_bounds__(256) void linear8_kernel(
    const float* __restrict__ X, const float* __restrict__ W,
    const float* __restrict__ bias, float* __restrict__ Y,
    int K, int O, int doRelu)
{
    int o = blockIdx.x;
    const float* wr = W + (size_t)o * K;
    float acc[BATCH];
    #pragma unroll
    for (int b = 0; b < BATCH; ++b) acc[b] = 0.f;
    for (int k = threadIdx.x; k < K; k += 256) {
        float wv = wr[k];
        #pragma unroll
        for (int b = 0; b < BATCH; ++b)
            acc[b] = fmaf(X[(size_t)b * K + k], wv, acc[b]);
    }
    __shared__ float red[4][BATCH];
    int lane = threadIdx.x & 63, wid = threadIdx.x >> 6;
    #pragma unroll
    for (int b = 0; b < BATCH; ++b) {
        float v = acc[b];
        #pragma unroll
        for (int off = 32; off > 0; off >>= 1) v += __shfl_down(v, off, 64);
        if (lane == 0) red[wid][b] = v;
    }
    __syncthreads();
    if (threadIdx.x < BATCH) {
        float v = red[0][threadIdx.x] + red[1][threadIdx.x] +
                  red[2][threadIdx.x] + red[3][threadIdx.x];
        v += bias[o];
        if (doRelu) v = fmaxf(v, 0.f);
        Y[(size_t)threadIdx.x * O + o] = v;
    }
}

// ---------------- zero init ----------------
__global__ __launch_bounds__(256) void zero_kernel(float* __restrict__ p, int n)
{
    int i = blockIdx.x * 256 + threadIdx.x;
    if (i < n) p[i] = 0.f;
}

// ---------------- one LSTM step ----------------
// thread = (b, j); computes 4 gates for hidden unit j of batch b
__global__ __launch_bounds__(256) void lstm_step_kernel(
    const float* __restrict__ embed_W, const int* __restrict__ tokens,
    const float* __restrict__ w_ih, const float* __restrict__ w_hh,
    const float* __restrict__ b_ih, const float* __restrict__ b_hh,
    const float* __restrict__ h_in, const float* __restrict__ c_in,
    float* __restrict__ h_out, float* __restrict__ c_out, int t)
{
    int idx = blockIdx.x * 256 + threadIdx.x;  // 0 .. B*HDIM-1
    int b = idx >> 9;
    int j = idx & (HDIM - 1);
    int tok = (t == 0) ? START_TOK : tokens[b * T_STEPS + (t - 1)];
    const float* e = embed_W + (size_t)tok * EDIM;
    const float* hb = h_in + (size_t)b * HDIM;
    float g[4];
    #pragma unroll
    for (int q = 0; q < 4; ++q) {
        int row = q * HDIM + j;
        float a = b_ih[row] + b_hh[row];
        const float* wi = w_ih + (size_t)row * EDIM;
        for (int k = 0; k < EDIM; ++k) a = fmaf(e[k], wi[k], a);
        const float* wh = w_hh + (size_t)row * HDIM;
        for (int k = 0; k < HDIM; ++k) a = fmaf(hb[k], wh[k], a);
        g[q] = a;
    }
    float ig = 1.f / (1.f + expf(-g[0]));
    float fg = 1.f / (1.f + expf(-g[1]));
    float gg = tanhf(g[2]);
    float og = 1.f / (1.f + expf(-g[3]));
    float c = fg * c_in[idx] + ig * gg;
    float h = og * tanhf(c);
    c_out[idx] = c;
    h_out[idx] = h;
}

// ---------------- decode: proj_rnn + relu + scores + log_softmax ----------------
// one 64-thread block per (t, b)
__global__ __launch_bounds__(64) void decode_kernel(
    const float* __restrict__ hs, const float* __restrict__ proj_rnn_w,
    const float* __restrict__ proj_rnn_b, const float* __restrict__ img_emb,
    const float* __restrict__ embed_W, float* __restrict__ out)
{
    int bid = blockIdx.x;        // t*B + b
    int t = bid >> 3;
    int b = bid & 7;
    int e = threadIdx.x;         // 0..63
    const float* hrow = hs + ((size_t)t * BATCH + b) * HDIM;
    float a = proj_rnn_b[e] + img_emb[b * EDIM + e];
    const float* wr = proj_rnn_w + (size_t)e * HDIM;
    for (int k = 0; k < HDIM; ++k) a = fmaf(hrow[k], wr[k], a);
    a = fmaxf(a, 0.f);
    __shared__ float xdec[EDIM];
    __shared__ float sc[VOCAB];
    xdec[e] = a;
    __syncthreads();
    if (e < VOCAB) {
        float s = 0.f;
        if (e == START_TOK) {
            for (int k = 0; k < EDIM; ++k) s += xdec[k];
            s *= -1e9f;
        } else {
            const float* w2 = embed_W + (size_t)e * EDIM;
            for (int k = 0; k < EDIM; ++k) s = fmaf(xdec[k], w2[k], s);
        }
        sc[e] = s;
    }
    __syncthreads();
    if (e == 0) {
        float m = -INFINITY;
        for (int v = 0; v < VOCAB; ++v) m = fmaxf(m, sc[v]);
        float sum = 0.f;
        for (int v = 0; v < VOCAB; ++v) sum += expf(sc[v] - m);
        float lse = m + logf(sum);
        for (int v = 0; v < VOCAB; ++v)
            out[((size_t)b * T_STEPS + t) * VOCAB + v] = sc[v] - lse;
    }
}

// ---------------- host launch ----------------
static const int CIN_[13]  = {3, 64, 64, 128, 128, 256, 256, 256, 512, 512, 512, 512, 512};
static const int COUT_[13] = {64, 64, 128, 128, 256, 256, 256, 512, 512, 512, 512, 512, 512};
static const int HSZ_[13]  = {224, 224, 112, 112, 56, 56, 56, 28, 28, 28, 14, 14, 14};
static const bool POOL_[13] = {false, true, false, true, false, false, true,
                               false, false, true, false, false, true};

extern "C" void kernel_launch(void* const* d_in, const int* in_sizes, int n_in,
                              void* d_out, int out_size, void* d_ws, size_t ws_size,
                              hipStream_t stream) {
    // inputs
    const float* fc1_w = (const float*)d_in[26];
    const float* fc1_b = (const float*)d_in[27];
    const float* fc2_w = (const float*)d_in[28];
    const float* fc2_b = (const float*)d_in[29];
    const float* embed_W = (const float*)d_in[30];
    const float* w_ih = (const float*)d_in[31];
    const float* w_hh = (const float*)d_in[32];
    const float* b_ih = (const float*)d_in[33];
    const float* b_hh = (const float*)d_in[34];
    const float* proj_rnn_w = (const float*)d_in[35];
    const float* proj_rnn_b = (const float*)d_in[36];
    const float* proj_img_w = (const float*)d_in[37];
    const float* proj_img_b = (const float*)d_in[38];
    const float* images = (const float*)d_in[39];
    const int* tokens = (const int*)d_in[40];
    float* out = (float*)d_out;

    // workspace carve-up
    char* p = (char*)d_ws;
    auto alloc = [&](size_t nbytes) -> float* {
        float* r = (float*)p;
        p += (nbytes + 255) & ~(size_t)255;
        return r;
    };
    const size_t MAXACT = (size_t)BATCH * 64 * 224 * 224;  // 25,690,112 floats
    float* bufs[2];
    bufs[0] = alloc(MAXACT * 4);
    bufs[1] = alloc(MAXACT * 4);
    float* f1 = alloc((size_t)BATCH * 4096 * 4);
    float* f2 = alloc((size_t)BATCH * 4096 * 4);
    float* img_emb = alloc((size_t)BATCH * EDIM * 4);
    float* zeros = alloc((size_t)BATCH * HDIM * 4);
    float* cbuf = alloc((size_t)BATCH * HDIM * 4);
    float* hs = alloc((size_t)T_STEPS * BATCH * HDIM * 4);

    // ---- VGG conv stack ----
    int di = 0;
    const float* cur = images;
    for (int i = 0; i < 13; ++i) {
        int Hs = HSZ_[i], Ws = Hs, HW = Hs * Ws;
        float* dst = bufs[di]; di ^= 1;
        dim3 grid((HW + 255) / 256, COUT_[i], BATCH);
        conv3x3_relu_kernel<<<grid, 256, 0, stream>>>(
            cur, (const float*)d_in[2 * i], (const float*)d_in[2 * i + 1], dst,
            CIN_[i], COUT_[i], Hs, Ws);
        cur = dst;
        if (POOL_[i]) {
            float* pdst = bufs[di]; di ^= 1;
            size_t total = (size_t)BATCH * COUT_[i] * (Hs / 2) * (Ws / 2);
            maxpool2_kernel<<<(int)((total + 255) / 256), 256, 0, stream>>>(
                cur, pdst, COUT_[i], Hs, Ws);
            cur = pdst;
        }
    }
    // cur now holds [B, 512, 7, 7] = [B, 25088]

    // ---- classifier ----
    linear8_kernel<<<4096, 256, 0, stream>>>(cur, fc1_w, fc1_b, f1, 25088, 4096, 1);
    linear8_kernel<<<4096, 256, 0, stream>>>(f1, fc2_w, fc2_b, f2, 4096, 4096, 1);
    linear8_kernel<<<64, 256, 0, stream>>>(f2, proj_img_w, proj_img_b, img_emb, 4096, 64, 0);

    // ---- LSTM ----
    zero_kernel<<<16, 256, 0, stream>>>(zeros, BATCH * HDIM);
    for (int t = 0; t < T_STEPS; ++t) {
        const float* h_in = (t == 0) ? zeros : (hs + (size_t)(t - 1) * BATCH * HDIM);
        const float* c_in = (t == 0) ? zeros : cbuf;
        lstm_step_kernel<<<16, 256, 0, stream>>>(
            embed_W, tokens, w_ih, w_hh, b_ih, b_hh,
            h_in, c_in, hs + (size_t)t * BATCH * HDIM, cbuf, t);
    }

    // ---- decode ----
    decode_kernel<<<T_STEPS * BATCH, 64, 0, stream>>>(
        hs, proj_rnn_w, proj_rnn_b, img_emb, embed_W, out);
}

// Round 2
// 8697.595 us; speedup vs baseline: 6.4891x; 6.4891x over previous
//
#include <hip/hip_runtime.h>
#include <hip/hip_bf16.h>
#include <math.h>
#include <utility>

#define BATCH 8
#define T_STEPS 20
#define VOCAB 22
#define EDIM 64
#define HDIM 512
#define START_TOK 20

#define KC 8
#define XS_ROWS 6
#define XS_COLS 18

// ---------------- weight transpose: w[Cout][Cin][9] -> wt[Cin][9][Cout] ----
__global__ __launch_bounds__(256) void transpose_w_kernel(
    const float* __restrict__ w, float* __restrict__ wt, int Cin, int Cout)
{
    size_t total = (size_t)Cout * Cin * 9;
    size_t idx = (size_t)blockIdx.x * 256 + threadIdx.x;
    if (idx >= total) return;
    int o = (int)(idx % Cout);
    size_t rest = idx / Cout;
    int tap = (int)(rest % 9);
    int ic = (int)(rest / 9);
    wt[idx] = w[((size_t)o * Cin + ic) * 9 + tap];
}

// ---------------- tiled conv 3x3 SAME + relu, Cin % 8 == 0 ----------------
// block: 256 threads = 16 cols (tx) x 16 o-groups (ty, 4 consecutive o each)
// tile: 64 o x (4 rows x 16 cols); K staged in chunks of KC=8 channels
__global__ __launch_bounds__(256) void conv_tiled_kernel(
    const float* __restrict__ x, const float* __restrict__ wt,
    const float* __restrict__ bias, float* __restrict__ y,
    int Cin, int Cout, int H, int W, int tiles_c)
{
    int tile = blockIdx.x;
    int tr = tile / tiles_c, tc = tile - tr * tiles_c;
    int r0 = tr * 4, c0 = tc * 16;
    int n = blockIdx.z;
    int ob = blockIdx.y * 64;
    int tx = threadIdx.x & 15;   // col within tile
    int ty = threadIdx.x >> 4;   // o-group (4 consecutive o)

    __shared__ float xs[KC][XS_ROWS][XS_COLS];
    __shared__ float ws[KC][9][64];

    float acc[4][4];
    #pragma unroll
    for (int r = 0; r < 4; ++r)
        #pragma unroll
        for (int j = 0; j < 4; ++j) acc[r][j] = 0.f;

    const float* xn = x + (size_t)n * Cin * H * W;

    for (int ic0 = 0; ic0 < Cin; ic0 += KC) {
        // stage X tile (with halo), zero-padded at borders
        for (int idx = threadIdx.x; idx < KC * XS_ROWS * XS_COLS; idx += 256) {
            int lc = idx % XS_COLS;
            int rest = idx / XS_COLS;
            int lr = rest % XS_ROWS;
            int i = rest / XS_ROWS;
            int gr = r0 - 1 + lr, gc = c0 - 1 + lc;
            float v = 0.f;
            if ((unsigned)gr < (unsigned)H && (unsigned)gc < (unsigned)W)
                v = xn[((size_t)(ic0 + i) * H + gr) * W + gc];
            xs[i][lr][lc] = v;
        }
        // stage W slice (coalesced thanks to pre-transpose)
        for (int idx = threadIdx.x; idx < KC * 9 * 64; idx += 256) {
            int o = idx & 63;
            int rest = idx >> 6;
            int tap = rest % 9;
            int i = rest / 9;
            ws[i][tap][o] = wt[((size_t)(ic0 + i) * 9 + tap) * Cout + ob + o];
        }
        __syncthreads();

        #pragma unroll 2
        for (int i = 0; i < KC; ++i) {
            float xr[XS_ROWS][3];
            #pragma unroll
            for (int lr = 0; lr < XS_ROWS; ++lr)
                #pragma unroll
                for (int k = 0; k < 3; ++k)
                    xr[lr][k] = xs[i][lr][tx + k];
            #pragma unroll
            for (int kh = 0; kh < 3; ++kh)
                #pragma unroll
                for (int kw = 0; kw < 3; ++kw) {
                    float4 wv = *(const float4*)&ws[i][kh * 3 + kw][ty * 4];
                    #pragma unroll
                    for (int r = 0; r < 4; ++r) {
                        float xv = xr[r + kh][kw];
                        acc[r][0] = fmaf(xv, wv.x, acc[r][0]);
                        acc[r][1] = fmaf(xv, wv.y, acc[r][1]);
                        acc[r][2] = fmaf(xv, wv.z, acc[r][2]);
                        acc[r][3] = fmaf(xv, wv.w, acc[r][3]);
                    }
                }
        }
        __syncthreads();
    }

    // epilogue: bias + relu + store (masked)
    float4 bv = *(const float4*)&bias[ob + ty * 4];
    int col = c0 + tx;
    if (col < W) {
        #pragma unroll
        for (int r = 0; r < 4; ++r) {
            int row = r0 + r;
            if (row >= H) break;
            #pragma unroll
            for (int j = 0; j < 4; ++j) {
                int o = ob + ty * 4 + j;
                float bj = (j == 0) ? bv.x : (j == 1) ? bv.y : (j == 2) ? bv.z : bv.w;
                y[((size_t)n * Cout + o) * H * W + (size_t)row * W + col] =
                    fmaxf(acc[r][j] + bj, 0.f);
            }
        }
    }
}

// ---------------- conv 3x3 SAME + relu (direct; layer 1 only, Cin=3) ------
__global__ __launch_bounds__(256) void conv3x3_relu_kernel(
    const float* __restrict__ x, const float* __restrict__ w,
    const float* __restrict__ bias, float* __restrict__ y,
    int Cin, int Cout, int Hs, int Ws)
{
    int HW = Hs * Ws;
    int sp = blockIdx.x * 256 + threadIdx.x;
    if (sp >= HW) return;
    int h = sp / Ws;
    int col = sp - h * Ws;
    int o = blockIdx.y;
    int n = blockIdx.z;
    const float* xn = x + (size_t)n * Cin * HW;
    const float* wo = w + (size_t)o * Cin * 9;
    float acc = bias[o];
    if (h >= 1 && h < Hs - 1 && col >= 1 && col < Ws - 1) {
        const float* xr = xn + (size_t)(h - 1) * Ws + (col - 1);
        for (int i = 0; i < Cin; ++i) {
            const float* xc = xr + (size_t)i * HW;
            const float* wc = wo + i * 9;
            acc += xc[0] * wc[0] + xc[1] * wc[1] + xc[2] * wc[2];
            acc += xc[Ws] * wc[3] + xc[Ws + 1] * wc[4] + xc[Ws + 2] * wc[5];
            acc += xc[2 * Ws] * wc[6] + xc[2 * Ws + 1] * wc[7] + xc[2 * Ws + 2] * wc[8];
        }
    } else {
        for (int i = 0; i < Cin; ++i) {
            const float* xc = xn + (size_t)i * HW;
            const float* wc = wo + i * 9;
            #pragma unroll
            for (int kh = 0; kh < 3; ++kh) {
                int hh = h + kh - 1;
                if (hh < 0 || hh >= Hs) continue;
                #pragma unroll
                for (int kw = 0; kw < 3; ++kw) {
                    int cc = col + kw - 1;
                    if (cc < 0 || cc >= Ws) continue;
                    acc += xc[hh * Ws + cc] * wc[kh * 3 + kw];
                }
            }
        }
    }
    y[((size_t)n * Cout + o) * HW + sp] = fmaxf(acc, 0.f);
}

// ---------------- 2x2 maxpool stride 2 ----------------
__global__ __launch_bounds__(256) void maxpool2_kernel(
    const float* __restrict__ x, float* __restrict__ y, int C, int Hin, int Win)
{
    int Ho = Hin >> 1, Wo = Win >> 1;
    size_t total = (size_t)BATCH * C * Ho * Wo;
    size_t i = (size_t)blockIdx.x * 256 + threadIdx.x;
    if (i >= total) return;
    int wo = (int)(i % Wo);
    size_t r = i / Wo;
    int ho = (int)(r % Ho);
    r /= Ho;  // r = n*C + c
    const float* xp = x + (r * Hin + 2 * (size_t)ho) * Win + 2 * wo;
    float m = fmaxf(fmaxf(xp[0], xp[1]), fmaxf(xp[Win], xp[Win + 1]));
    y[i] = m;
}

// ---------------- linear: Y[b][o] = act(sum_k X[b][k]*W[o][k] + bias[o]) ----
__global__ __launch_bounds__(256) void linear8_kernel(
    const float* __restrict__ X, const float* __restrict__ W,
    const float* __restrict__ bias, float* __restrict__ Y,
    int K, int O, int doRelu)
{
    int o = blockIdx.x;
    const float* wr = W + (size_t)o * K;
    float acc[BATCH];
    #pragma unroll
    for (int b = 0; b < BATCH; ++b) acc[b] = 0.f;
    for (int k = threadIdx.x; k < K; k += 256) {
        float wv = wr[k];
        #pragma unroll
        for (int b = 0; b < BATCH; ++b)
            acc[b] = fmaf(X[(size_t)b * K + k], wv, acc[b]);
    }
    __shared__ float red[4][BATCH];
    int lane = threadIdx.x & 63, wid = threadIdx.x >> 6;
    #pragma unroll
    for (int b = 0; b < BATCH; ++b) {
        float v = acc[b];
        #pragma unroll
        for (int off = 32; off > 0; off >>= 1) v += __shfl_down(v, off, 64);
        if (lane == 0) red[wid][b] = v;
    }
    __syncthreads();
    if (threadIdx.x < BATCH) {
        float v = red[0][threadIdx.x] + red[1][threadIdx.x] +
                  red[2][threadIdx.x] + red[3][threadIdx.x];
        v += bias[o];
        if (doRelu) v = fmaxf(v, 0.f);
        Y[(size_t)threadIdx.x * O + o] = v;
    }
}

// ---------------- zero init ----------------
__global__ __launch_bounds__(256) void zero_kernel(float* __restrict__ p, int n)
{
    int i = blockIdx.x * 256 + threadIdx.x;
    if (i < n) p[i] = 0.f;
}

// ---------------- one LSTM step ----------------
__global__ __launch_bounds__(256) void lstm_step_kernel(
    const float* __restrict__ embed_W, const int* __restrict__ tokens,
    const float* __restrict__ w_ih, const float* __restrict__ w_hh,
    const float* __restrict__ b_ih, const float* __restrict__ b_hh,
    const float* __restrict__ h_in, const float* __restrict__ c_in,
    float* __restrict__ h_out, float* __restrict__ c_out, int t)
{
    int idx = blockIdx.x * 256 + threadIdx.x;  // 0 .. B*HDIM-1
    int b = idx >> 9;
    int j = idx & (HDIM - 1);
    int tok = (t == 0) ? START_TOK : tokens[b * T_STEPS + (t - 1)];
    const float* e = embed_W + (size_t)tok * EDIM;
    const float* hb = h_in + (size_t)b * HDIM;
    float g[4];
    #pragma unroll
    for (int q = 0; q < 4; ++q) {
        int row = q * HDIM + j;
        float a = b_ih[row] + b_hh[row];
        const float* wi = w_ih + (size_t)row * EDIM;
        for (int k = 0; k < EDIM; ++k) a = fmaf(e[k], wi[k], a);
        const float* wh = w_hh + (size_t)row * HDIM;
        for (int k = 0; k < HDIM; ++k) a = fmaf(hb[k], wh[k], a);
        g[q] = a;
    }
    float ig = 1.f / (1.f + expf(-g[0]));
    float fg = 1.f / (1.f + expf(-g[1]));
    float gg = tanhf(g[2]);
    float og = 1.f / (1.f + expf(-g[3]));
    float c = fg * c_in[idx] + ig * gg;
    float h = og * tanhf(c);
    c_out[idx] = c;
    h_out[idx] = h;
}

// ---------------- decode: proj_rnn + relu + scores + log_softmax ----------
__global__ __launch_bounds__(64) void decode_kernel(
    const float* __restrict__ hs, const float* __restrict__ proj_rnn_w,
    const float* __restrict__ proj_rnn_b, const float* __restrict__ img_emb,
    const float* __restrict__ embed_W, float* __restrict__ out)
{
    int bid = blockIdx.x;        // t*B + b
    int t = bid >> 3;
    int b = bid & 7;
    int e = threadIdx.x;         // 0..63
    const float* hrow = hs + ((size_t)t * BATCH + b) * HDIM;
    float a = proj_rnn_b[e] + img_emb[b * EDIM + e];
    const float* wr = proj_rnn_w + (size_t)e * HDIM;
    for (int k = 0; k < HDIM; ++k) a = fmaf(hrow[k], wr[k], a);
    a = fmaxf(a, 0.f);
    __shared__ float xdec[EDIM];
    __shared__ float sc[VOCAB];
    xdec[e] = a;
    __syncthreads();
    if (e < VOCAB) {
        float s = 0.f;
        if (e == START_TOK) {
            for (int k = 0; k < EDIM; ++k) s += xdec[k];
            s *= -1e9f;
        } else {
            const float* w2 = embed_W + (size_t)e * EDIM;
            for (int k = 0; k < EDIM; ++k) s = fmaf(xdec[k], w2[k], s);
        }
        sc[e] = s;
    }
    __syncthreads();
    if (e == 0) {
        float m = -INFINITY;
        for (int v = 0; v < VOCAB; ++v) m = fmaxf(m, sc[v]);
        float sum = 0.f;
        for (int v = 0; v < VOCAB; ++v) sum += expf(sc[v] - m);
        float lse = m + logf(sum);
        for (int v = 0; v < VOCAB; ++v)
            out[((size_t)b * T_STEPS + t) * VOCAB + v] = sc[v] - lse;
    }
}

// ---------------- host launch ----------------
static const int CIN_[13]  = {3, 64, 64, 128, 128, 256, 256, 256, 512, 512, 512, 512, 512};
static const int COUT_[13] = {64, 64, 128, 128, 256, 256, 256, 512, 512, 512, 512, 512, 512};
static const int HSZ_[13]  = {224, 224, 112, 112, 56, 56, 56, 28, 28, 28, 14, 14, 14};
static const bool POOL_[13] = {false, true, false, true, false, false, true,
                               false, false, true, false, false, true};

extern "C" void kernel_launch(void* const* d_in, const int* in_sizes, int n_in,
                              void* d_out, int out_size, void* d_ws, size_t ws_size,
                              hipStream_t stream) {
    const float* fc1_w = (const float*)d_in[26];
    const float* fc1_b = (const float*)d_in[27];
    const float* fc2_w = (const float*)d_in[28];
    const float* fc2_b = (const float*)d_in[29];
    const float* embed_W = (const float*)d_in[30];
    const float* w_ih = (const float*)d_in[31];
    const float* w_hh = (const float*)d_in[32];
    const float* b_ih = (const float*)d_in[33];
    const float* b_hh = (const float*)d_in[34];
    const float* proj_rnn_w = (const float*)d_in[35];
    const float* proj_rnn_b = (const float*)d_in[36];
    const float* proj_img_w = (const float*)d_in[37];
    const float* proj_img_b = (const float*)d_in[38];
    const float* images = (const float*)d_in[39];
    const int* tokens = (const int*)d_in[40];
    float* out = (float*)d_out;

    char* p = (char*)d_ws;
    auto alloc = [&](size_t nbytes) -> float* {
        float* r = (float*)p;
        p += (nbytes + 255) & ~(size_t)255;
        return r;
    };
    const size_t MAXACT = (size_t)BATCH * 64 * 224 * 224;  // 25,690,112 floats
    float* bufs[2];
    bufs[0] = alloc(MAXACT * 4);
    bufs[1] = alloc(MAXACT * 4);
    float* f1 = alloc((size_t)BATCH * 4096 * 4);
    float* f2 = alloc((size_t)BATCH * 4096 * 4);
    float* img_emb = alloc((size_t)BATCH * EDIM * 4);
    float* zeros = alloc((size_t)BATCH * HDIM * 4);
    float* cbuf = alloc((size_t)BATCH * HDIM * 4);
    float* hs = alloc((size_t)T_STEPS * BATCH * HDIM * 4);
    float* wt = alloc((size_t)512 * 9 * 512 * 4);  // transposed weights (max 9.4MB)

    // ---- VGG conv stack ----
    int di = 0;
    const float* cur = images;
    for (int i = 0; i < 13; ++i) {
        int Hs = HSZ_[i], Ws = Hs, HW = Hs * Ws;
        float* dst = bufs[di]; di ^= 1;
        if (i == 0) {
            dim3 grid((HW + 255) / 256, COUT_[i], BATCH);
            conv3x3_relu_kernel<<<grid, 256, 0, stream>>>(
                cur, (const float*)d_in[0], (const float*)d_in[1], dst,
                CIN_[i], COUT_[i], Hs, Ws);
        } else {
            size_t wtotal = (size_t)COUT_[i] * CIN_[i] * 9;
            transpose_w_kernel<<<(int)((wtotal + 255) / 256), 256, 0, stream>>>(
                (const float*)d_in[2 * i], wt, CIN_[i], COUT_[i]);
            int tiles_r = (Hs + 3) / 4, tiles_c = (Ws + 15) / 16;
            dim3 grid(tiles_r * tiles_c, COUT_[i] / 64, BATCH);
            conv_tiled_kernel<<<grid, 256, 0, stream>>>(
                cur, wt, (const float*)d_in[2 * i + 1], dst,
                CIN_[i], COUT_[i], Hs, Ws, tiles_c);
        }
        cur = dst;
        if (POOL_[i]) {
            float* pdst = bufs[di]; di ^= 1;
            size_t total = (size_t)BATCH * COUT_[i] * (Hs / 2) * (Ws / 2);
            maxpool2_kernel<<<(int)((total + 255) / 256), 256, 0, stream>>>(
                cur, pdst, COUT_[i], Hs, Ws);
            cur = pdst;
        }
    }

    // ---- classifier ----
    linear8_kernel<<<4096, 256, 0, stream>>>(cur, fc1_w, fc1_b, f1, 25088, 4096, 1);
    linear8_kernel<<<4096, 256, 0, stream>>>(f1, fc2_w, fc2_b, f2, 4096, 4096, 1);
    linear8_kernel<<<64, 256, 0, stream>>>(f2, proj_img_w, proj_img_b, img_emb, 4096, 64, 0);

    // ---- LSTM ----
    zero_kernel<<<16, 256, 0, stream>>>(zeros, BATCH * HDIM);
    for (int t = 0; t < T_STEPS; ++t) {
        const float* h_in = (t == 0) ? zeros : (hs + (size_t)(t - 1) * BATCH * HDIM);
        const float* c_in = (t == 0) ? zeros : cbuf;
        lstm_step_kernel<<<16, 256, 0, stream>>>(
            embed_W, tokens, w_ih, w_hh, b_ih, b_hh,
            h_in, c_in, hs + (size_t)t * BATCH * HDIM, cbuf, t);
    }

    // ---- decode ----
    decode_kernel<<<T_STEPS * BATCH, 64, 0, stream>>>(
        hs, proj_rnn_w, proj_rnn_b, img_emb, embed_W, out);
}